// Round 4
// baseline (314.825 us; speedup 1.0000x reference)
//
#include <hip/hip_runtime.h>
#include <hip/hip_bf16.h>
#include <stdint.h>

#define DEV __device__ __forceinline__

typedef __attribute__((ext_vector_type(8))) short short8;
typedef __attribute__((ext_vector_type(8))) __bf16 bf16x8;
typedef __attribute__((ext_vector_type(4))) float f32x4;

typedef const __attribute__((address_space(1))) uint32_t gu32;
typedef __attribute__((address_space(3))) uint32_t lu32;

DEV void gload16(const void* g, void* l) {
  __builtin_amdgcn_global_load_lds((gu32*)g, (lu32*)l, 16, 0, 0);
}

DEV f32x4 mfma16(bf16x8 a, bf16x8 b, f32x4 c) {
  return __builtin_amdgcn_mfma_f32_16x16x32_bf16(a, b, c, 0, 0, 0);
}

DEV __hip_bfloat16 f2bf(float x) { return __float2bfloat16(x); }
DEV bf16x8 as_bf(short8 v) { union { short8 s; bf16x8 b; } u; u.s = v; return u.b; }

// ---------------------------------------------------------------------------
// f32 -> bf16 elementwise convert (n multiple of 8).
// ---------------------------------------------------------------------------
__global__ __launch_bounds__(256)
void cvt_f32_bf16(const float* __restrict__ src, __hip_bfloat16* __restrict__ dst, int n)
{
  int i = (blockIdx.x * 256 + threadIdx.x) * 8;
  if (i >= n) return;
  f32x4 a = *(const f32x4*)&src[i];
  f32x4 b = *(const f32x4*)&src[i + 4];
  short8 o;
#pragma unroll
  for (int j = 0; j < 4; ++j) {
    o[j]     = __bfloat16_as_short(f2bf(a[j]));
    o[j + 4] = __bfloat16_as_short(f2bf(b[j]));
  }
  *(short8*)&dst[i] = o;
}

// ---------------------------------------------------------------------------
// Transpose f32 [K][N] -> bf16 [N][K], 64x64 tiles, 256 threads.
// ---------------------------------------------------------------------------
__global__ __launch_bounds__(256)
void transpose_cvt(const float* __restrict__ src,
                   __hip_bfloat16* __restrict__ dst,
                   int K, int N)
{
  __shared__ __hip_bfloat16 tile[64][72];
  const int tid = threadIdx.x;
  const int k0 = blockIdx.y * 64, n0 = blockIdx.x * 64;
  const int r = tid >> 3, c8 = tid & 7;
#pragma unroll
  for (int i = 0; i < 2; ++i) {
    int k = r + i * 32;
    f32x4 a = *(const f32x4*)&src[(size_t)(k0 + k) * N + n0 + c8 * 8];
    f32x4 b = *(const f32x4*)&src[(size_t)(k0 + k) * N + n0 + c8 * 8 + 4];
#pragma unroll
    for (int j = 0; j < 4; ++j) {
      tile[k][c8 * 8 + j]     = f2bf(a[j]);
      tile[k][c8 * 8 + 4 + j] = f2bf(b[j]);
    }
  }
  __syncthreads();
#pragma unroll
  for (int i = 0; i < 2; ++i) {
    int n = r + i * 32;
    short8 v;
#pragma unroll
    for (int j = 0; j < 8; ++j) v[j] = *(const short*)&tile[c8 * 8 + j][n];
    *(short8*)&dst[(size_t)(n0 + n) * K + k0 + c8 * 8] = v;
  }
}

// ---------------------------------------------------------------------------
// 128x128-tile GEMM (m97 structure), mode 0: C = A*Bt^T + bias (f32 out).
// Used for the dense projection.
// ---------------------------------------------------------------------------
__global__ __launch_bounds__(256)
void gemm_bt(const __hip_bfloat16* __restrict__ A,
             const __hip_bfloat16* __restrict__ Bt,
             const float* __restrict__ bias,
             float* __restrict__ C,
             int M, int N, int K)
{
  __shared__ __hip_bfloat16 As[128 * 64];
  __shared__ __hip_bfloat16 Bs[128 * 64];

  const int tid = threadIdx.x;
  const int lane = tid & 63;
  const int wave = tid >> 6;
  const int wm = wave >> 1, wn = wave & 1;
  const int m0 = blockIdx.y * 128, n0 = blockIdx.x * 128;
  const int fr = lane & 15, fq = lane >> 4;

  const int sc = wave * 4;
  const int srow = lane >> 3;
  const int scol = lane & 7;

  f32x4 acc[4][4] = {};
  const char* Ab = (const char*)As;
  const char* Bb = (const char*)Bs;

  for (int k0 = 0; k0 < K; k0 += 64) {
#pragma unroll
    for (int i = 0; i < 4; ++i) {
      int c = sc + i;
      int rr = c * 8 + srow;
      int kk = (scol ^ (rr & 7)) << 3;
      gload16(&A[(size_t)(m0 + rr) * K + k0 + kk], &As[c * 512]);
    }
#pragma unroll
    for (int i = 0; i < 4; ++i) {
      int c = sc + i;
      int rr = c * 8 + srow;
      int kk = (scol ^ (rr & 7)) << 3;
      gload16(&Bt[(size_t)(n0 + rr) * K + k0 + kk], &Bs[c * 512]);
    }
    __syncthreads();
#pragma unroll
    for (int kk = 0; kk < 2; ++kk) {
      bf16x8 af[4], bfv[4];
#pragma unroll
      for (int mi = 0; mi < 4; ++mi) {
        int row = wm * 64 + mi * 16 + fr;
        int cb = (kk * 64 + fq * 16) ^ ((row & 7) << 4);
        af[mi] = as_bf(*(const short8*)(Ab + row * 128 + cb));
      }
#pragma unroll
      for (int ni = 0; ni < 4; ++ni) {
        int row = wn * 64 + ni * 16 + fr;
        int cb = (kk * 64 + fq * 16) ^ ((row & 7) << 4);
        bfv[ni] = as_bf(*(const short8*)(Bb + row * 128 + cb));
      }
#pragma unroll
      for (int mi = 0; mi < 4; ++mi)
#pragma unroll
        for (int ni = 0; ni < 4; ++ni)
          acc[mi][ni] = mfma16(af[mi], bfv[ni], acc[mi][ni]);
    }
    __syncthreads();
  }

#pragma unroll
  for (int ni = 0; ni < 4; ++ni) {
    int n = n0 + wn * 64 + ni * 16 + fr;
    float bv = bias[n];
#pragma unroll
    for (int mi = 0; mi < 4; ++mi) {
      int mbase = m0 + wm * 64 + mi * 16 + fq * 4;
#pragma unroll
      for (int j = 0; j < 4; ++j)
        C[(size_t)(mbase + j) * N + n] = acc[mi][ni][j] + bv;
    }
  }
}

// ---------------------------------------------------------------------------
// 256x256-tile QKV GEMM, BK=64, 8 waves (2Mx4N), deep-pipelined (T3+T4):
// per K-tile 4 phases x 16 MFMA; next tile staged as 4 half-units (Aa,B0,B1,Ab)
// one per phase; counted vmcnt(4)/vmcnt(6) + raw s_barrier at phases 0/2 only.
// T2 swizzle (linear LDS dest + inverse-swizzled global src + swizzled read).
// T5 setprio around MFMA clusters. Epilogue scatters q/k/v^T.
// ---------------------------------------------------------------------------
__global__ __launch_bounds__(512, 2)
void gemm256_qkv(const __hip_bfloat16* __restrict__ A,
                 const __hip_bfloat16* __restrict__ Bt,
                 const float* __restrict__ bias,
                 __hip_bfloat16* __restrict__ qb,
                 __hip_bfloat16* __restrict__ kb,
                 __hip_bfloat16* __restrict__ vtb,
                 int M, int N, int K)
{
  __shared__ __hip_bfloat16 As[2][256 * 64];
  __shared__ __hip_bfloat16 Bs[2][256 * 64];

  const int tid = threadIdx.x, lane = tid & 63, wave = tid >> 6;
  const int wm = wave >> 2, wn = wave & 3;
  const int m0 = blockIdx.y * 256, n0 = blockIdx.x * 256;
  const int fr = lane & 15, fq = lane >> 4;
  const int lrow = lane >> 3, lslot = lane & 7;
  const int s0 = wave * 2, s1 = wave * 2 + 1;   // 16 spans of 8 rows per unit

  // span row-bases for the four units
  const int ra0_0 = (s0 < 8) ? s0 * 8 : 128 + (s0 - 8) * 8;  // A-alpha
  const int ra0_1 = (s1 < 8) ? s1 * 8 : 128 + (s1 - 8) * 8;
  const int ra1_0 = (s0 < 8) ? 64 + s0 * 8 : 192 + (s0 - 8) * 8;  // A-beta
  const int ra1_1 = (s1 < 8) ? 64 + s1 * 8 : 192 + (s1 - 8) * 8;
  const int rb0_0 = s0 * 8,       rb0_1 = s1 * 8;        // B rows 0-127
  const int rb1_0 = 128 + s0 * 8, rb1_1 = 128 + s1 * 8;  // B rows 128-255

  auto stage = [&](const __hip_bfloat16* src, int row0, int row_base, int k0,
                   __hip_bfloat16* ldsTile) {
    int rr = row_base + lrow;
    int col = k0 + ((lslot ^ (rr & 7)) << 3);
    gload16(&src[(size_t)(row0 + rr) * K + col], (char*)ldsTile + row_base * 128);
  };

  f32x4 acc[8][4] = {};
  const int kt = K / 64;

  // prologue: all 4 units of tile 0, in the canonical order Aa,B0,B1,Ab
  stage(A, m0, ra0_0, 0, &As[0][0]); stage(A, m0, ra0_1, 0, &As[0][0]);
  stage(Bt, n0, rb0_0, 0, &Bs[0][0]); stage(Bt, n0, rb0_1, 0, &Bs[0][0]);
  stage(Bt, n0, rb1_0, 0, &Bs[0][0]); stage(Bt, n0, rb1_1, 0, &Bs[0][0]);
  stage(A, m0, ra1_0, 0, &As[0][0]); stage(A, m0, ra1_1, 0, &As[0][0]);

  for (int t = 0; t < kt; ++t) {
    const int buf = t & 1, nbuf = buf ^ 1;
    const int k1 = (t + 1) * 64;
    const bool pre = (t + 1 < kt);
    const char* Ab = (const char*)&As[buf][0];
    const char* Bb = (const char*)&Bs[buf][0];
    bf16x8 bfr[4][2];

    // ---- phase 0: issue Aa(t+1); wait Aa/B0/B1(t); MFMA m0-3 kk0 ----
    __builtin_amdgcn_sched_barrier(0);
    if (pre) { stage(A, m0, ra0_0, k1, &As[nbuf][0]); stage(A, m0, ra0_1, k1, &As[nbuf][0]); }
    if (pre) asm volatile("s_waitcnt vmcnt(4)" ::: "memory");
    else     asm volatile("s_waitcnt vmcnt(2)" ::: "memory");
    __builtin_amdgcn_s_barrier();
    __builtin_amdgcn_sched_barrier(0);
    {
      bf16x8 af[4];
#pragma unroll
      for (int mi = 0; mi < 4; ++mi) {
        int row = wm * 128 + mi * 16 + fr;
        af[mi] = as_bf(*(const short8*)(Ab + row * 128 + ((fq * 16) ^ ((row & 7) << 4))));
      }
#pragma unroll
      for (int ni = 0; ni < 4; ++ni) {
        int row = wn * 64 + ni * 16 + fr;
        bfr[ni][0] = as_bf(*(const short8*)(Bb + row * 128 + ((fq * 16) ^ ((row & 7) << 4))));
      }
      __builtin_amdgcn_s_setprio(1);
#pragma unroll
      for (int mi = 0; mi < 4; ++mi)
#pragma unroll
        for (int ni = 0; ni < 4; ++ni)
          acc[mi][ni] = mfma16(af[mi], bfr[ni][0], acc[mi][ni]);
      __builtin_amdgcn_s_setprio(0);
    }

    // ---- phase 1: issue B0(t+1); MFMA m0-3 kk1 ----
    __builtin_amdgcn_sched_barrier(0);
    if (pre) { stage(Bt, n0, rb0_0, k1, &Bs[nbuf][0]); stage(Bt, n0, rb0_1, k1, &Bs[nbuf][0]); }
    {
      bf16x8 af[4];
#pragma unroll
      for (int mi = 0; mi < 4; ++mi) {
        int row = wm * 128 + mi * 16 + fr;
        af[mi] = as_bf(*(const short8*)(Ab + row * 128 + ((64 + fq * 16) ^ ((row & 7) << 4))));
      }
#pragma unroll
      for (int ni = 0; ni < 4; ++ni) {
        int row = wn * 64 + ni * 16 + fr;
        bfr[ni][1] = as_bf(*(const short8*)(Bb + row * 128 + ((64 + fq * 16) ^ ((row & 7) << 4))));
      }
      __builtin_amdgcn_s_setprio(1);
#pragma unroll
      for (int mi = 0; mi < 4; ++mi)
#pragma unroll
        for (int ni = 0; ni < 4; ++ni)
          acc[mi][ni] = mfma16(af[mi], bfr[ni][1], acc[mi][ni]);
      __builtin_amdgcn_s_setprio(0);
    }

    // ---- phase 2: issue B1(t+1); wait Ab(t); MFMA m4-7 kk0 ----
    __builtin_amdgcn_sched_barrier(0);
    if (pre) { stage(Bt, n0, rb1_0, k1, &Bs[nbuf][0]); stage(Bt, n0, rb1_1, k1, &Bs[nbuf][0]); }
    if (pre) asm volatile("s_waitcnt vmcnt(6)" ::: "memory");
    else     asm volatile("s_waitcnt vmcnt(0)" ::: "memory");
    __builtin_amdgcn_s_barrier();
    __builtin_amdgcn_sched_barrier(0);
    {
      bf16x8 af[4];
#pragma unroll
      for (int mi = 0; mi < 4; ++mi) {
        int row = wm * 128 + (mi + 4) * 16 + fr;
        af[mi] = as_bf(*(const short8*)(Ab + row * 128 + ((fq * 16) ^ ((row & 7) << 4))));
      }
      __builtin_amdgcn_s_setprio(1);
#pragma unroll
      for (int mi = 0; mi < 4; ++mi)
#pragma unroll
        for (int ni = 0; ni < 4; ++ni)
          acc[mi + 4][ni] = mfma16(af[mi], bfr[ni][0], acc[mi + 4][ni]);
      __builtin_amdgcn_s_setprio(0);
    }

    // ---- phase 3: issue Ab(t+1); MFMA m4-7 kk1 ----
    __builtin_amdgcn_sched_barrier(0);
    if (pre) { stage(A, m0, ra1_0, k1, &As[nbuf][0]); stage(A, m0, ra1_1, k1, &As[nbuf][0]); }
    {
      bf16x8 af[4];
#pragma unroll
      for (int mi = 0; mi < 4; ++mi) {
        int row = wm * 128 + (mi + 4) * 16 + fr;
        af[mi] = as_bf(*(const short8*)(Ab + row * 128 + ((64 + fq * 16) ^ ((row & 7) << 4))));
      }
      __builtin_amdgcn_s_setprio(1);
#pragma unroll
      for (int mi = 0; mi < 4; ++mi)
#pragma unroll
        for (int ni = 0; ni < 4; ++ni)
          acc[mi + 4][ni] = mfma16(af[mi], bfr[ni][1], acc[mi + 4][ni]);
      __builtin_amdgcn_s_setprio(0);
    }
  }

  // epilogue: scatter to q/k/v^T. Per-ni the (head, qkv-type) is uniform.
#pragma unroll
  for (int ni = 0; ni < 4; ++ni) {
    const int nb = n0 + wn * 64 + ni * 16;       // multiple of 16
    const int h = nb / 384;
    const int rb = nb - h * 384;
    const int t3 = rb >> 7;
    const int dloc = (rb & 127) + fr;            // head-dim index
    const float bv = bias[nb + fr];
#pragma unroll
    for (int mi = 0; mi < 8; ++mi) {
      const int mbase = m0 + wm * 128 + mi * 16 + fq * 4;
#pragma unroll
      for (int j = 0; j < 4; ++j) {
        const int m = mbase + j;
        const int b = m >> 11, s = m & 2047;
        const int bh = b * 16 + h;
        const float v = acc[mi][ni][j] + bv;
        if (t3 == 0)      qb[((size_t)bh * 2048 + s) * 128 + dloc] = f2bf(v);
        else if (t3 == 1) kb[((size_t)bh * 2048 + s) * 128 + dloc] = f2bf(v);
        else              vtb[((size_t)bh * 128 + dloc) * 2048 + s] = f2bf(v);
      }
    }
  }
}

// ---------------------------------------------------------------------------
// Causal flash attention (r3 structure: heavy-first, double-buffered, setprio).
// ---------------------------------------------------------------------------
__global__ __launch_bounds__(256)
void attn_kernel(const __hip_bfloat16* __restrict__ qb,
                 const __hip_bfloat16* __restrict__ kb,
                 const __hip_bfloat16* __restrict__ vtb,
                 __hip_bfloat16* __restrict__ ctx)
{
  __shared__ __hip_bfloat16 Ks[2][64 * 128];
  __shared__ __hip_bfloat16 Vts[2][128 * 64];
  __shared__ __hip_bfloat16 Ps[4][16 * 64];

  const int tid = threadIdx.x, lane = tid & 63, wave = tid >> 6;
  const int fr = lane & 15, fq = lane >> 4;
  const int blk = blockIdx.x;
  const int qi = 31 - (blk >> 5);
  const int bh = blk & 31;
  const int q0 = qi * 64;

  bf16x8 qf[4];
  const int qrow = q0 + wave * 16 + fr;
#pragma unroll
  for (int kf = 0; kf < 4; ++kf)
    qf[kf] = as_bf(*(const short8*)&qb[((size_t)bh * 2048 + qrow) * 128 + kf * 32 + fq * 8]);

  f32x4 acco[8] = {};
  float m_run[4] = {-1e30f, -1e30f, -1e30f, -1e30f};
  float l_run[4] = {0.f, 0.f, 0.f, 0.f};

  char* Pb = (char*)&Ps[wave][0];
  const int nt = qi + 1;

  auto STAGE = [&](int t, int buf) {
    const int k0t = t * 64;
#pragma unroll
    for (int i = 0; i < 4; ++i) {
      int c = wave * 4 + i;
      int kv = c * 4 + fq;
      int cb = (fr * 16) ^ ((kv & 7) << 4);
      gload16(&kb[((size_t)bh * 2048 + k0t + kv) * 128 + (cb >> 1)], &Ks[buf][c * 512]);
    }
#pragma unroll
    for (int i = 0; i < 4; ++i) {
      int c = wave * 4 + i;
      int d = c * 8 + (lane >> 3);
      int cb = ((lane & 7) * 16) ^ ((d & 7) << 4);
      gload16(&vtb[((size_t)bh * 128 + d) * 2048 + k0t + (cb >> 1)], &Vts[buf][c * 512]);
    }
  };

  STAGE(0, 0);
  __syncthreads();

  int cur = 0;
  for (int t = 0; t < nt; ++t) {
    if (t + 1 < nt) STAGE(t + 1, cur ^ 1);
    const char* Kb = (const char*)&Ks[cur][0];
    const char* Vb = (const char*)&Vts[cur][0];
    const int k0 = t * 64;

    f32x4 sacc[4] = {};
    __builtin_amdgcn_s_setprio(1);
#pragma unroll
    for (int kf = 0; kf < 4; ++kf) {
#pragma unroll
      for (int ni = 0; ni < 4; ++ni) {
        int kv = ni * 16 + fr;
        int cb = (kf * 64 + fq * 16) ^ ((kv & 7) << 4);
        bf16x8 kfr = as_bf(*(const short8*)(Kb + kv * 256 + cb));
        sacc[ni] = mfma16(qf[kf], kfr, sacc[ni]);
      }
    }
    __builtin_amdgcn_s_setprio(0);

    const float scale = 0.088388347648318447f;
    float sv[4][4];
    float rmax[4] = {-1e30f, -1e30f, -1e30f, -1e30f};
#pragma unroll
    for (int ni = 0; ni < 4; ++ni) {
      int kv_g = k0 + ni * 16 + fr;
#pragma unroll
      for (int j = 0; j < 4; ++j) {
        int q_g = q0 + wave * 16 + fq * 4 + j;
        float s = sacc[ni][j] * scale;
        if (kv_g > q_g) s = -10000.f;
        sv[ni][j] = s;
        rmax[j] = fmaxf(rmax[j], s);
      }
    }
#pragma unroll
    for (int off = 1; off < 16; off <<= 1)
#pragma unroll
      for (int j = 0; j < 4; ++j)
        rmax[j] = fmaxf(rmax[j], __shfl_xor(rmax[j], off));

    float alpha[4], rsum[4];
#pragma unroll
    for (int j = 0; j < 4; ++j) {
      float mn = fmaxf(m_run[j], rmax[j]);
      alpha[j] = __expf(m_run[j] - mn);
      m_run[j] = mn;
      rsum[j] = 0.f;
    }
#pragma unroll
    for (int ni = 0; ni < 4; ++ni) {
#pragma unroll
      for (int j = 0; j < 4; ++j) {
        float p = __expf(sv[ni][j] - m_run[j]);
        rsum[j] += p;
        int prow = fq * 4 + j;
        int cbw = ((ni * 16 + fr) * 2) ^ ((prow & 7) << 4);
        *(__hip_bfloat16*)(Pb + prow * 128 + cbw) = f2bf(p);
      }
    }
#pragma unroll
    for (int off = 1; off < 16; off <<= 1)
#pragma unroll
      for (int j = 0; j < 4; ++j)
        rsum[j] += __shfl_xor(rsum[j], off);
#pragma unroll
    for (int j = 0; j < 4; ++j)
      l_run[j] = l_run[j] * alpha[j] + rsum[j];

#pragma unroll
    for (int nd = 0; nd < 8; ++nd)
#pragma unroll
      for (int j = 0; j < 4; ++j)
        acco[nd][j] *= alpha[j];

    asm volatile("s_waitcnt lgkmcnt(0)" ::: "memory");
    __builtin_amdgcn_sched_barrier(0);

    __builtin_amdgcn_s_setprio(1);
#pragma unroll
    for (int kf2 = 0; kf2 < 2; ++kf2) {
      int cbp = (kf2 * 64 + fq * 16) ^ ((fr & 7) << 4);
      bf16x8 pa = as_bf(*(const short8*)(Pb + fr * 128 + cbp));
#pragma unroll
      for (int nd = 0; nd < 8; ++nd) {
        int d = nd * 16 + fr;
        int cbv = (kf2 * 64 + fq * 16) ^ ((d & 7) << 4);
        bf16x8 vfr = as_bf(*(const short8*)(Vb + d * 128 + cbv));
        acco[nd] = mfma16(pa, vfr, acco[nd]);
      }
    }
    __builtin_amdgcn_s_setprio(0);
    __syncthreads();
    cur ^= 1;
  }

  const int b = bh >> 4, h = bh & 15;
#pragma unroll
  for (int j = 0; j < 4; ++j) {
    float inv = 1.f / l_run[j];
    int s = q0 + wave * 16 + fq * 4 + j;
#pragma unroll
    for (int nd = 0; nd < 8; ++nd) {
      int d = nd * 16 + fr;
      ctx[(((size_t)b * 2048 + s) * 16 + h) * 128 + d] = f2bf(acco[nd][j] * inv);
    }
  }
}

// ---------------------------------------------------------------------------
extern "C" void kernel_launch(void* const* d_in, const int* in_sizes, int n_in,
                              void* d_out, int out_size, void* d_ws, size_t ws_size,
                              hipStream_t stream)
{
  (void)in_sizes; (void)n_in; (void)out_size; (void)ws_size;
  const float* x       = (const float*)d_in[0];
  const float* w_qkv   = (const float*)d_in[1];
  const float* b_qkv   = (const float*)d_in[2];
  const float* w_dense = (const float*)d_in[3];
  const float* b_dense = (const float*)d_in[4];
  float* out = (float*)d_out;

  char* ws = (char*)d_ws;
  __hip_bfloat16* x_bf     = (__hip_bfloat16*)(ws);                  // 16MB
  __hip_bfloat16* wqkv_t   = (__hip_bfloat16*)(ws + 16777216);       // 24MB
  __hip_bfloat16* wdense_t = (__hip_bfloat16*)(ws + 41943040);       // 8MB
  __hip_bfloat16* qb       = (__hip_bfloat16*)(ws + 50331648);       // 16MB
  __hip_bfloat16* kb       = (__hip_bfloat16*)(ws + 67108864);       // 16MB
  __hip_bfloat16* vtb      = (__hip_bfloat16*)(ws + 83886080);       // 16MB
  __hip_bfloat16* ctx      = (__hip_bfloat16*)(ws + 100663296);      // 16MB

  cvt_f32_bf16<<<4096, 256, 0, stream>>>(x, x_bf, 4096 * 2048);
  transpose_cvt<<<dim3(96, 32), 256, 0, stream>>>(w_qkv, wqkv_t, 2048, 6144);
  transpose_cvt<<<dim3(32, 32), 256, 0, stream>>>(w_dense, wdense_t, 2048, 2048);
  gemm256_qkv<<<dim3(24, 16), 512, 0, stream>>>(x_bf, wqkv_t, b_qkv,
                                                qb, kb, vtb, 4096, 6144, 2048);
  attn_kernel<<<1024, 256, 0, stream>>>(qb, kb, vtb, ctx);
  gemm_bt<<<dim3(16, 32), 256, 0, stream>>>(ctx, wdense_t, b_dense, out,
                                            4096, 2048, 2048);
}

// Round 5
// 304.210 us; speedup vs baseline: 1.0349x; 1.0349x over previous
//
#include <hip/hip_runtime.h>
#include <hip/hip_bf16.h>
#include <stdint.h>

#define DEV __device__ __forceinline__

typedef __attribute__((ext_vector_type(8))) short short8;
typedef __attribute__((ext_vector_type(8))) __bf16 bf16x8;
typedef __attribute__((ext_vector_type(4))) float f32x4;

typedef const __attribute__((address_space(1))) uint32_t gu32;
typedef __attribute__((address_space(3))) uint32_t lu32;

DEV void gload16(const void* g, void* l) {
  __builtin_amdgcn_global_load_lds((gu32*)g, (lu32*)l, 16, 0, 0);
}

DEV f32x4 mfma16(bf16x8 a, bf16x8 b, f32x4 c) {
  return __builtin_amdgcn_mfma_f32_16x16x32_bf16(a, b, c, 0, 0, 0);
}

DEV __hip_bfloat16 f2bf(float x) { return __float2bfloat16(x); }
DEV bf16x8 as_bf(short8 v) { union { short8 s; bf16x8 b; } u; u.s = v; return u.b; }

// ---------------------------------------------------------------------------
// f32 -> bf16 elementwise convert (n multiple of 8).
// ---------------------------------------------------------------------------
__global__ __launch_bounds__(256)
void cvt_f32_bf16(const float* __restrict__ src, __hip_bfloat16* __restrict__ dst, int n)
{
  int i = (blockIdx.x * 256 + threadIdx.x) * 8;
  if (i >= n) return;
  f32x4 a = *(const f32x4*)&src[i];
  f32x4 b = *(const f32x4*)&src[i + 4];
  short8 o;
#pragma unroll
  for (int j = 0; j < 4; ++j) {
    o[j]     = __bfloat16_as_short(f2bf(a[j]));
    o[j + 4] = __bfloat16_as_short(f2bf(b[j]));
  }
  *(short8*)&dst[i] = o;
}

// ---------------------------------------------------------------------------
// Transpose f32 [K][N] -> bf16 [N][K], 64x64 tiles, 256 threads.
// ---------------------------------------------------------------------------
__global__ __launch_bounds__(256)
void transpose_cvt(const float* __restrict__ src,
                   __hip_bfloat16* __restrict__ dst,
                   int K, int N)
{
  __shared__ __hip_bfloat16 tile[64][72];
  const int tid = threadIdx.x;
  const int k0 = blockIdx.y * 64, n0 = blockIdx.x * 64;
  const int r = tid >> 3, c8 = tid & 7;
#pragma unroll
  for (int i = 0; i < 2; ++i) {
    int k = r + i * 32;
    f32x4 a = *(const f32x4*)&src[(size_t)(k0 + k) * N + n0 + c8 * 8];
    f32x4 b = *(const f32x4*)&src[(size_t)(k0 + k) * N + n0 + c8 * 8 + 4];
#pragma unroll
    for (int j = 0; j < 4; ++j) {
      tile[k][c8 * 8 + j]     = f2bf(a[j]);
      tile[k][c8 * 8 + 4 + j] = f2bf(b[j]);
    }
  }
  __syncthreads();
#pragma unroll
  for (int i = 0; i < 2; ++i) {
    int n = r + i * 32;
    short8 v;
#pragma unroll
    for (int j = 0; j < 8; ++j) v[j] = *(const short*)&tile[c8 * 8 + j][n];
    *(short8*)&dst[(size_t)(n0 + n) * K + k0 + c8 * 8] = v;
  }
}

// ---------------------------------------------------------------------------
// 128x128-tile GEMM (m97 structure): C = A*Bt^T + bias (f32 out).
// Used for the dense projection.
// ---------------------------------------------------------------------------
__global__ __launch_bounds__(256)
void gemm_bt(const __hip_bfloat16* __restrict__ A,
             const __hip_bfloat16* __restrict__ Bt,
             const float* __restrict__ bias,
             float* __restrict__ C,
             int M, int N, int K)
{
  __shared__ __hip_bfloat16 As[128 * 64];
  __shared__ __hip_bfloat16 Bs[128 * 64];

  const int tid = threadIdx.x;
  const int lane = tid & 63;
  const int wave = tid >> 6;
  const int wm = wave >> 1, wn = wave & 1;
  const int m0 = blockIdx.y * 128, n0 = blockIdx.x * 128;
  const int fr = lane & 15, fq = lane >> 4;

  const int sc = wave * 4;
  const int srow = lane >> 3;
  const int scol = lane & 7;

  f32x4 acc[4][4] = {};
  const char* Ab = (const char*)As;
  const char* Bb = (const char*)Bs;

  for (int k0 = 0; k0 < K; k0 += 64) {
#pragma unroll
    for (int i = 0; i < 4; ++i) {
      int c = sc + i;
      int rr = c * 8 + srow;
      int kk = (scol ^ (rr & 7)) << 3;
      gload16(&A[(size_t)(m0 + rr) * K + k0 + kk], &As[c * 512]);
    }
#pragma unroll
    for (int i = 0; i < 4; ++i) {
      int c = sc + i;
      int rr = c * 8 + srow;
      int kk = (scol ^ (rr & 7)) << 3;
      gload16(&Bt[(size_t)(n0 + rr) * K + k0 + kk], &Bs[c * 512]);
    }
    __syncthreads();
#pragma unroll
    for (int kk = 0; kk < 2; ++kk) {
      bf16x8 af[4], bfv[4];
#pragma unroll
      for (int mi = 0; mi < 4; ++mi) {
        int row = wm * 64 + mi * 16 + fr;
        int cb = (kk * 64 + fq * 16) ^ ((row & 7) << 4);
        af[mi] = as_bf(*(const short8*)(Ab + row * 128 + cb));
      }
#pragma unroll
      for (int ni = 0; ni < 4; ++ni) {
        int row = wn * 64 + ni * 16 + fr;
        int cb = (kk * 64 + fq * 16) ^ ((row & 7) << 4);
        bfv[ni] = as_bf(*(const short8*)(Bb + row * 128 + cb));
      }
#pragma unroll
      for (int mi = 0; mi < 4; ++mi)
#pragma unroll
        for (int ni = 0; ni < 4; ++ni)
          acc[mi][ni] = mfma16(af[mi], bfv[ni], acc[mi][ni]);
    }
    __syncthreads();
  }

#pragma unroll
  for (int ni = 0; ni < 4; ++ni) {
    int n = n0 + wn * 64 + ni * 16 + fr;
    float bv = bias[n];
#pragma unroll
    for (int mi = 0; mi < 4; ++mi) {
      int mbase = m0 + wm * 64 + mi * 16 + fq * 4;
#pragma unroll
      for (int j = 0; j < 4; ++j)
        C[(size_t)(mbase + j) * N + n] = acc[mi][ni][j] + bv;
    }
  }
}

// ---------------------------------------------------------------------------
// 256x256-tile QKV GEMM, BK=64, 8 waves (2Mx4N), m201-style fine phases:
// per K-tile 4 phases, each {ds_read subtile | stage 1 unit | barrier |
// setprio MFMA x16 | barrier} = 8 barriers/K-tile. Counted vmcnt at 2 points
// (entry vmcnt(2), post-q1 vmcnt(6)); issue-to-wait distance = 3 phases.
// Units: Aa (A rows for mi0-3), B0, B1, Ab (A rows for mi4-7).
// T2 swizzle; T5 setprio. Epilogue scatters q/k/v^T.
// ---------------------------------------------------------------------------
__global__ __launch_bounds__(512, 2)
void gemm256_qkv(const __hip_bfloat16* __restrict__ A,
                 const __hip_bfloat16* __restrict__ Bt,
                 const float* __restrict__ bias,
                 __hip_bfloat16* __restrict__ qb,
                 __hip_bfloat16* __restrict__ kb,
                 __hip_bfloat16* __restrict__ vtb,
                 int M, int N, int K)
{
  __shared__ __hip_bfloat16 As[2][256 * 64];
  __shared__ __hip_bfloat16 Bs[2][256 * 64];

  const int tid = threadIdx.x, lane = tid & 63, wave = tid >> 6;
  const int wm = wave >> 2, wn = wave & 3;
  const int m0 = blockIdx.y * 256, n0 = blockIdx.x * 256;
  const int fr = lane & 15, fq = lane >> 4;
  const int lrow = lane >> 3, lslot = lane & 7;
  const int s0 = wave * 2, s1 = wave * 2 + 1;   // 8-row spans per stage call

  // span row-bases for the four units
  const int ra0_0 = (s0 < 8) ? s0 * 8 : 128 + (s0 - 8) * 8;       // Aa: mi0-3 rows
  const int ra0_1 = (s1 < 8) ? s1 * 8 : 128 + (s1 - 8) * 8;
  const int ra1_0 = (s0 < 8) ? 64 + s0 * 8 : 192 + (s0 - 8) * 8;  // Ab: mi4-7 rows
  const int ra1_1 = (s1 < 8) ? 64 + s1 * 8 : 192 + (s1 - 8) * 8;
  const int rb0_0 = s0 * 8,       rb0_1 = s1 * 8;                 // B rows 0-127
  const int rb1_0 = 128 + s0 * 8, rb1_1 = 128 + s1 * 8;           // B rows 128-255

  auto stage = [&](const __hip_bfloat16* src, int row0, int row_base, int k0,
                   __hip_bfloat16* ldsTile) {
    int rr = row_base + lrow;
    int col = k0 + ((lslot ^ (rr & 7)) << 3);
    gload16(&src[(size_t)(row0 + rr) * K + col], (char*)ldsTile + row_base * 128);
  };

  f32x4 acc[8][4] = {};
  const int kt = K / 64;

  // prologue: all 4 units of tile 0
  stage(A, m0, ra0_0, 0, &As[0][0]); stage(A, m0, ra0_1, 0, &As[0][0]);
  stage(Bt, n0, rb0_0, 0, &Bs[0][0]); stage(Bt, n0, rb0_1, 0, &Bs[0][0]);
  stage(Bt, n0, rb1_0, 0, &Bs[0][0]); stage(Bt, n0, rb1_1, 0, &Bs[0][0]);
  stage(A, m0, ra1_0, 0, &As[0][0]); stage(A, m0, ra1_1, 0, &As[0][0]);

  for (int t = 0; t < kt; ++t) {
    const int buf = t & 1, nbuf = buf ^ 1;
    const int k1 = (t + 1) * 64;
    const bool pre = (t + 1 < kt);
    const char* Ab = (const char*)&As[buf][0];
    const char* Bb = (const char*)&Bs[buf][0];
    bf16x8 b0[4], b1[4];

    // entry gate: Aa,B0,B1 of tile t landed (Ab still in flight)
    asm volatile("s_waitcnt vmcnt(2)" ::: "memory");
    __builtin_amdgcn_s_barrier();

    // ---- q0: reads A(mi0-3,kk0)+B(kk0); stage Aa,B0(t+1); MFMA kk0 upper ----
    {
      bf16x8 af[4];
#pragma unroll
      for (int mi = 0; mi < 4; ++mi) {
        int row = wm * 128 + mi * 16 + fr;
        af[mi] = as_bf(*(const short8*)(Ab + row * 128 + ((fq * 16) ^ ((row & 7) << 4))));
      }
#pragma unroll
      for (int ni = 0; ni < 4; ++ni) {
        int row = wn * 64 + ni * 16 + fr;
        b0[ni] = as_bf(*(const short8*)(Bb + row * 128 + ((fq * 16) ^ ((row & 7) << 4))));
      }
      if (pre) {
        stage(A, m0, ra0_0, k1, &As[nbuf][0]); stage(A, m0, ra0_1, k1, &As[nbuf][0]);
        stage(Bt, n0, rb0_0, k1, &Bs[nbuf][0]); stage(Bt, n0, rb0_1, k1, &Bs[nbuf][0]);
      }
      __builtin_amdgcn_s_barrier();
      __builtin_amdgcn_s_setprio(1);
#pragma unroll
      for (int mi = 0; mi < 4; ++mi)
#pragma unroll
        for (int ni = 0; ni < 4; ++ni)
          acc[mi][ni] = mfma16(af[mi], b0[ni], acc[mi][ni]);
      __builtin_amdgcn_s_setprio(0);
      __builtin_amdgcn_s_barrier();
    }

    // ---- q1: reads A(mi0-3,kk1)+B(kk1); stage B1(t+1); gate Ab(t); MFMA ----
    {
      bf16x8 af[4];
#pragma unroll
      for (int mi = 0; mi < 4; ++mi) {
        int row = wm * 128 + mi * 16 + fr;
        af[mi] = as_bf(*(const short8*)(Ab + row * 128 + ((64 + fq * 16) ^ ((row & 7) << 4))));
      }
#pragma unroll
      for (int ni = 0; ni < 4; ++ni) {
        int row = wn * 64 + ni * 16 + fr;
        b1[ni] = as_bf(*(const short8*)(Bb + row * 128 + ((64 + fq * 16) ^ ((row & 7) << 4))));
      }
      if (pre) {
        stage(Bt, n0, rb1_0, k1, &Bs[nbuf][0]); stage(Bt, n0, rb1_1, k1, &Bs[nbuf][0]);
        asm volatile("s_waitcnt vmcnt(6)" ::: "memory");
      } else {
        asm volatile("s_waitcnt vmcnt(0)" ::: "memory");
      }
      __builtin_amdgcn_s_barrier();
      __builtin_amdgcn_s_setprio(1);
#pragma unroll
      for (int mi = 0; mi < 4; ++mi)
#pragma unroll
        for (int ni = 0; ni < 4; ++ni)
          acc[mi][ni] = mfma16(af[mi], b1[ni], acc[mi][ni]);
      __builtin_amdgcn_s_setprio(0);
      __builtin_amdgcn_s_barrier();
    }

    // ---- q2: reads A(mi4-7,kk0); stage Ab(t+1); MFMA (reuse b0) ----
    {
      bf16x8 af[4];
#pragma unroll
      for (int mi = 0; mi < 4; ++mi) {
        int row = wm * 128 + (mi + 4) * 16 + fr;
        af[mi] = as_bf(*(const short8*)(Ab + row * 128 + ((fq * 16) ^ ((row & 7) << 4))));
      }
      if (pre) {
        stage(A, m0, ra1_0, k1, &As[nbuf][0]); stage(A, m0, ra1_1, k1, &As[nbuf][0]);
      }
      __builtin_amdgcn_s_barrier();
      __builtin_amdgcn_s_setprio(1);
#pragma unroll
      for (int mi = 0; mi < 4; ++mi)
#pragma unroll
        for (int ni = 0; ni < 4; ++ni)
          acc[mi + 4][ni] = mfma16(af[mi], b0[ni], acc[mi + 4][ni]);
      __builtin_amdgcn_s_setprio(0);
      __builtin_amdgcn_s_barrier();
    }

    // ---- q3: reads A(mi4-7,kk1); MFMA (reuse b1); closing barrier ----
    {
      bf16x8 af[4];
#pragma unroll
      for (int mi = 0; mi < 4; ++mi) {
        int row = wm * 128 + (mi + 4) * 16 + fr;
        af[mi] = as_bf(*(const short8*)(Ab + row * 128 + ((64 + fq * 16) ^ ((row & 7) << 4))));
      }
      __builtin_amdgcn_s_barrier();
      __builtin_amdgcn_s_setprio(1);
#pragma unroll
      for (int mi = 0; mi < 4; ++mi)
#pragma unroll
        for (int ni = 0; ni < 4; ++ni)
          acc[mi + 4][ni] = mfma16(af[mi], b1[ni], acc[mi + 4][ni]);
      __builtin_amdgcn_s_setprio(0);
      __builtin_amdgcn_s_barrier();
    }
  }

  // epilogue: scatter to q/k/v^T. Per-ni the (head, qkv-type) is uniform.
#pragma unroll
  for (int ni = 0; ni < 4; ++ni) {
    const int nb = n0 + wn * 64 + ni * 16;       // multiple of 16
    const int h = nb / 384;
    const int rb = nb - h * 384;
    const int t3 = rb >> 7;
    const int dloc = (rb & 127) + fr;            // head-dim index
    const float bv = bias[nb + fr];
#pragma unroll
    for (int mi = 0; mi < 8; ++mi) {
      const int mbase = m0 + wm * 128 + mi * 16 + fq * 4;
#pragma unroll
      for (int j = 0; j < 4; ++j) {
        const int m = mbase + j;
        const int b = m >> 11, s = m & 2047;
        const int bh = b * 16 + h;
        const float v = acc[mi][ni][j] + bv;
        if (t3 == 0)      qb[((size_t)bh * 2048 + s) * 128 + dloc] = f2bf(v);
        else if (t3 == 1) kb[((size_t)bh * 2048 + s) * 128 + dloc] = f2bf(v);
        else              vtb[((size_t)bh * 128 + dloc) * 2048 + s] = f2bf(v);
      }
    }
  }
}

// ---------------------------------------------------------------------------
// Causal flash attention (heavy-first, double-buffered, setprio).
// ---------------------------------------------------------------------------
__global__ __launch_bounds__(256)
void attn_kernel(const __hip_bfloat16* __restrict__ qb,
                 const __hip_bfloat16* __restrict__ kb,
                 const __hip_bfloat16* __restrict__ vtb,
                 __hip_bfloat16* __restrict__ ctx)
{
  __shared__ __hip_bfloat16 Ks[2][64 * 128];
  __shared__ __hip_bfloat16 Vts[2][128 * 64];
  __shared__ __hip_bfloat16 Ps[4][16 * 64];

  const int tid = threadIdx.x, lane = tid & 63, wave = tid >> 6;
  const int fr = lane & 15, fq = lane >> 4;
  const int blk = blockIdx.x;
  const int qi = 31 - (blk >> 5);
  const int bh = blk & 31;
  const int q0 = qi * 64;

  bf16x8 qf[4];
  const int qrow = q0 + wave * 16 + fr;
#pragma unroll
  for (int kf = 0; kf < 4; ++kf)
    qf[kf] = as_bf(*(const short8*)&qb[((size_t)bh * 2048 + qrow) * 128 + kf * 32 + fq * 8]);

  f32x4 acco[8] = {};
  float m_run[4] = {-1e30f, -1e30f, -1e30f, -1e30f};
  float l_run[4] = {0.f, 0.f, 0.f, 0.f};

  char* Pb = (char*)&Ps[wave][0];
  const int nt = qi + 1;

  auto STAGE = [&](int t, int buf) {
    const int k0t = t * 64;
#pragma unroll
    for (int i = 0; i < 4; ++i) {
      int c = wave * 4 + i;
      int kv = c * 4 + fq;
      int cb = (fr * 16) ^ ((kv & 7) << 4);
      gload16(&kb[((size_t)bh * 2048 + k0t + kv) * 128 + (cb >> 1)], &Ks[buf][c * 512]);
    }
#pragma unroll
    for (int i = 0; i < 4; ++i) {
      int c = wave * 4 + i;
      int d = c * 8 + (lane >> 3);
      int cb = ((lane & 7) * 16) ^ ((d & 7) << 4);
      gload16(&vtb[((size_t)bh * 128 + d) * 2048 + k0t + (cb >> 1)], &Vts[buf][c * 512]);
    }
  };

  STAGE(0, 0);
  __syncthreads();

  int cur = 0;
  for (int t = 0; t < nt; ++t) {
    if (t + 1 < nt) STAGE(t + 1, cur ^ 1);
    const char* Kb = (const char*)&Ks[cur][0];
    const char* Vb = (const char*)&Vts[cur][0];
    const int k0 = t * 64;

    f32x4 sacc[4] = {};
    __builtin_amdgcn_s_setprio(1);
#pragma unroll
    for (int kf = 0; kf < 4; ++kf) {
#pragma unroll
      for (int ni = 0; ni < 4; ++ni) {
        int kv = ni * 16 + fr;
        int cb = (kf * 64 + fq * 16) ^ ((kv & 7) << 4);
        bf16x8 kfr = as_bf(*(const short8*)(Kb + kv * 256 + cb));
        sacc[ni] = mfma16(qf[kf], kfr, sacc[ni]);
      }
    }
    __builtin_amdgcn_s_setprio(0);

    const float scale = 0.088388347648318447f;
    float sv[4][4];
    float rmax[4] = {-1e30f, -1e30f, -1e30f, -1e30f};
#pragma unroll
    for (int ni = 0; ni < 4; ++ni) {
      int kv_g = k0 + ni * 16 + fr;
#pragma unroll
      for (int j = 0; j < 4; ++j) {
        int q_g = q0 + wave * 16 + fq * 4 + j;
        float s = sacc[ni][j] * scale;
        if (kv_g > q_g) s = -10000.f;
        sv[ni][j] = s;
        rmax[j] = fmaxf(rmax[j], s);
      }
    }
#pragma unroll
    for (int off = 1; off < 16; off <<= 1)
#pragma unroll
      for (int j = 0; j < 4; ++j)
        rmax[j] = fmaxf(rmax[j], __shfl_xor(rmax[j], off));

    float alpha[4], rsum[4];
#pragma unroll
    for (int j = 0; j < 4; ++j) {
      float mn = fmaxf(m_run[j], rmax[j]);
      alpha[j] = __expf(m_run[j] - mn);
      m_run[j] = mn;
      rsum[j] = 0.f;
    }
#pragma unroll
    for (int ni = 0; ni < 4; ++ni) {
#pragma unroll
      for (int j = 0; j < 4; ++j) {
        float p = __expf(sv[ni][j] - m_run[j]);
        rsum[j] += p;
        int prow = fq * 4 + j;
        int cbw = ((ni * 16 + fr) * 2) ^ ((prow & 7) << 4);
        *(__hip_bfloat16*)(Pb + prow * 128 + cbw) = f2bf(p);
      }
    }
#pragma unroll
    for (int off = 1; off < 16; off <<= 1)
#pragma unroll
      for (int j = 0; j < 4; ++j)
        rsum[j] += __shfl_xor(rsum[j], off);
#pragma unroll
    for (int j = 0; j < 4; ++j)
      l_run[j] = l_run[j] * alpha[j] + rsum[j];

#pragma unroll
    for (int nd = 0; nd < 8; ++nd)
#pragma unroll
      for (int j = 0; j < 4; ++j)
        acco[nd][j] *= alpha[j];

    asm volatile("s_waitcnt lgkmcnt(0)" ::: "memory");
    __builtin_amdgcn_sched_barrier(0);

    __builtin_amdgcn_s_setprio(1);
#pragma unroll
    for (int kf2 = 0; kf2 < 2; ++kf2) {
      int cbp = (kf2 * 64 + fq * 16) ^ ((fr & 7) << 4);
      bf16x8 pa = as_bf(*(const short8*)(Pb + fr * 128 + cbp));
#pragma unroll
      for (int nd = 0; nd < 8; ++nd) {
        int d = nd * 16 + fr;
        int cbv = (kf2 * 64 + fq * 16) ^ ((d & 7) << 4);
        bf16x8 vfr = as_bf(*(const short8*)(Vb + d * 128 + cbv));
        acco[nd] = mfma16(pa, vfr, acco[nd]);
      }
    }
    __builtin_amdgcn_s_setprio(0);
    __syncthreads();
    cur ^= 1;
  }

  const int b = bh >> 4, h = bh & 15;
#pragma unroll
  for (int j = 0; j < 4; ++j) {
    float inv = 1.f / l_run[j];
    int s = q0 + wave * 16 + fq * 4 + j;
#pragma unroll
    for (int nd = 0; nd < 8; ++nd) {
      int d = nd * 16 + fr;
      ctx[(((size_t)b * 2048 + s) * 16 + h) * 128 + d] = f2bf(acco[nd][j] * inv);
    }
  }
}

// ---------------------------------------------------------------------------
extern "C" void kernel_launch(void* const* d_in, const int* in_sizes, int n_in,
                              void* d_out, int out_size, void* d_ws, size_t ws_size,
                              hipStream_t stream)
{
  (void)in_sizes; (void)n_in; (void)out_size; (void)ws_size;
  const float* x       = (const float*)d_in[0];
  const float* w_qkv   = (const float*)d_in[1];
  const float* b_qkv   = (const float*)d_in[2];
  const float* w_dense = (const float*)d_in[3];
  const float* b_dense = (const float*)d_in[4];
  float* out = (float*)d_out;

  char* ws = (char*)d_ws;
  __hip_bfloat16* x_bf     = (__hip_bfloat16*)(ws);                  // 16MB
  __hip_bfloat16* wqkv_t   = (__hip_bfloat16*)(ws + 16777216);       // 24MB
  __hip_bfloat16* wdense_t = (__hip_bfloat16*)(ws + 41943040);       // 8MB
  __hip_bfloat16* qb       = (__hip_bfloat16*)(ws + 50331648);       // 16MB
  __hip_bfloat16* kb       = (__hip_bfloat16*)(ws + 67108864);       // 16MB
  __hip_bfloat16* vtb      = (__hip_bfloat16*)(ws + 83886080);       // 16MB
  __hip_bfloat16* ctx      = (__hip_bfloat16*)(ws + 100663296);      // 16MB

  cvt_f32_bf16<<<4096, 256, 0, stream>>>(x, x_bf, 4096 * 2048);
  transpose_cvt<<<dim3(96, 32), 256, 0, stream>>>(w_qkv, wqkv_t, 2048, 6144);
  transpose_cvt<<<dim3(32, 32), 256, 0, stream>>>(w_dense, wdense_t, 2048, 2048);
  gemm256_qkv<<<dim3(24, 16), 512, 0, stream>>>(x_bf, wqkv_t, b_qkv,
                                                qb, kb, vtb, 4096, 6144, 2048);
  attn_kernel<<<1024, 256, 0, stream>>>(qb, kb, vtb, ctx);
  gemm_bt<<<dim3(16, 32), 256, 0, stream>>>(ctx, wdense_t, b_dense, out,
                                            4096, 2048, 2048);
}

// Round 6
// 298.286 us; speedup vs baseline: 1.0554x; 1.0199x over previous
//
#include <hip/hip_runtime.h>
#include <hip/hip_bf16.h>
#include <stdint.h>

#define DEV __device__ __forceinline__

typedef __attribute__((ext_vector_type(8))) short short8;
typedef __attribute__((ext_vector_type(8))) __bf16 bf16x8;
typedef __attribute__((ext_vector_type(4))) float f32x4;

typedef const __attribute__((address_space(1))) uint32_t gu32;
typedef __attribute__((address_space(3))) uint32_t lu32;

DEV void gload16(const void* g, void* l) {
  __builtin_amdgcn_global_load_lds((gu32*)g, (lu32*)l, 16, 0, 0);
}

DEV f32x4 mfma16(bf16x8 a, bf16x8 b, f32x4 c) {
  return __builtin_amdgcn_mfma_f32_16x16x32_bf16(a, b, c, 0, 0, 0);
}

DEV __hip_bfloat16 f2bf(float x) { return __float2bfloat16(x); }
DEV bf16x8 as_bf(short8 v) { union { short8 s; bf16x8 b; } u; u.s = v; return u.b; }

// ---------------------------------------------------------------------------
// f32 -> bf16 elementwise convert (n multiple of 8).
// ---------------------------------------------------------------------------
__global__ __launch_bounds__(256)
void cvt_f32_bf16(const float* __restrict__ src, __hip_bfloat16* __restrict__ dst, int n)
{
  int i = (blockIdx.x * 256 + threadIdx.x) * 8;
  if (i >= n) return;
  f32x4 a = *(const f32x4*)&src[i];
  f32x4 b = *(const f32x4*)&src[i + 4];
  short8 o;
#pragma unroll
  for (int j = 0; j < 4; ++j) {
    o[j]     = __bfloat16_as_short(f2bf(a[j]));
    o[j + 4] = __bfloat16_as_short(f2bf(b[j]));
  }
  *(short8*)&dst[i] = o;
}

// ---------------------------------------------------------------------------
// Transpose f32 [K][N] -> bf16 [N][K], 64x64 tiles, 256 threads.
// ---------------------------------------------------------------------------
__global__ __launch_bounds__(256)
void transpose_cvt(const float* __restrict__ src,
                   __hip_bfloat16* __restrict__ dst,
                   int K, int N)
{
  __shared__ __hip_bfloat16 tile[64][72];
  const int tid = threadIdx.x;
  const int k0 = blockIdx.y * 64, n0 = blockIdx.x * 64;
  const int r = tid >> 3, c8 = tid & 7;
#pragma unroll
  for (int i = 0; i < 2; ++i) {
    int k = r + i * 32;
    f32x4 a = *(const f32x4*)&src[(size_t)(k0 + k) * N + n0 + c8 * 8];
    f32x4 b = *(const f32x4*)&src[(size_t)(k0 + k) * N + n0 + c8 * 8 + 4];
#pragma unroll
    for (int j = 0; j < 4; ++j) {
      tile[k][c8 * 8 + j]     = f2bf(a[j]);
      tile[k][c8 * 8 + 4 + j] = f2bf(b[j]);
    }
  }
  __syncthreads();
#pragma unroll
  for (int i = 0; i < 2; ++i) {
    int n = r + i * 32;
    short8 v;
#pragma unroll
    for (int j = 0; j < 8; ++j) v[j] = *(const short*)&tile[c8 * 8 + j][n];
    *(short8*)&dst[(size_t)(n0 + n) * K + k0 + c8 * 8] = v;
  }
}

// ---------------------------------------------------------------------------
// GEMM: C[M][N] = A[M][K](bf16) * Bt[N][K](bf16)^T + bias[N](f32)
// 128x128 tile, BK=64, 4 waves (2x2), 16x16x32 bf16 MFMA, global_load_lds,
// XOR-swizzled LDS. XCD-aware COLUMN-partitioned block swizzle:
// dispatch i -> XCD i%8 (hw round-robin); XCD k owns gx/8 consecutive
// B-panel columns and sweeps all M-rows reusing them (B-panels stay hot in
// that XCD's 4MB L2; A streams). Requires gridDim.x % 8 == 0.
// mode 0: write C (f32).  mode 1: scatter to q/k/v^T bf16 buffers.
// ---------------------------------------------------------------------------
__global__ __launch_bounds__(256)
void gemm_bt(const __hip_bfloat16* __restrict__ A,
             const __hip_bfloat16* __restrict__ Bt,
             const float* __restrict__ bias,
             float* __restrict__ C,
             __hip_bfloat16* __restrict__ qb,
             __hip_bfloat16* __restrict__ kb,
             __hip_bfloat16* __restrict__ vtb,
             int M, int N, int K, int mode)
{
  __shared__ __hip_bfloat16 As[128 * 64];
  __shared__ __hip_bfloat16 Bs[128 * 64];

  const int tid = threadIdx.x;
  const int lane = tid & 63;
  const int wave = tid >> 6;
  const int wm = wave >> 1, wn = wave & 1;

  // XCD column-partition swizzle
  const int gx = gridDim.x;
  const int cpx = gx >> 3;                       // B-panel columns per XCD
  const int lin = blockIdx.y * gx + blockIdx.x;
  const int xcd = lin & 7, t2 = lin >> 3;
  const int bx = xcd * cpx + (t2 % cpx);
  const int by = t2 / cpx;
  const int m0 = by * 128, n0 = bx * 128;

  const int fr = lane & 15, fq = lane >> 4;
  const int sc = wave * 4;
  const int srow = lane >> 3;
  const int scol = lane & 7;

  f32x4 acc[4][4] = {};
  const char* Ab = (const char*)As;
  const char* Bb = (const char*)Bs;

  for (int k0 = 0; k0 < K; k0 += 64) {
#pragma unroll
    for (int i = 0; i < 4; ++i) {
      int c = sc + i;
      int rr = c * 8 + srow;
      int kk = (scol ^ (rr & 7)) << 3;
      gload16(&A[(size_t)(m0 + rr) * K + k0 + kk], &As[c * 512]);
    }
#pragma unroll
    for (int i = 0; i < 4; ++i) {
      int c = sc + i;
      int rr = c * 8 + srow;
      int kk = (scol ^ (rr & 7)) << 3;
      gload16(&Bt[(size_t)(n0 + rr) * K + k0 + kk], &Bs[c * 512]);
    }
    __syncthreads();
#pragma unroll
    for (int kk = 0; kk < 2; ++kk) {
      bf16x8 af[4], bfv[4];
#pragma unroll
      for (int mi = 0; mi < 4; ++mi) {
        int row = wm * 64 + mi * 16 + fr;
        int cb = (kk * 64 + fq * 16) ^ ((row & 7) << 4);
        af[mi] = as_bf(*(const short8*)(Ab + row * 128 + cb));
      }
#pragma unroll
      for (int ni = 0; ni < 4; ++ni) {
        int row = wn * 64 + ni * 16 + fr;
        int cb = (kk * 64 + fq * 16) ^ ((row & 7) << 4);
        bfv[ni] = as_bf(*(const short8*)(Bb + row * 128 + cb));
      }
      __builtin_amdgcn_s_setprio(1);
#pragma unroll
      for (int mi = 0; mi < 4; ++mi)
#pragma unroll
        for (int ni = 0; ni < 4; ++ni)
          acc[mi][ni] = mfma16(af[mi], bfv[ni], acc[mi][ni]);
      __builtin_amdgcn_s_setprio(0);
    }
    __syncthreads();
  }

  if (mode == 0) {
#pragma unroll
    for (int ni = 0; ni < 4; ++ni) {
      int n = n0 + wn * 64 + ni * 16 + fr;
      float bv = bias[n];
#pragma unroll
      for (int mi = 0; mi < 4; ++mi) {
        int mbase = m0 + wm * 64 + mi * 16 + fq * 4;
#pragma unroll
        for (int j = 0; j < 4; ++j)
          C[(size_t)(mbase + j) * N + n] = acc[mi][ni][j] + bv;
      }
    }
  } else {
    // n0 multiple of 128; 384 = 3*128 so head h and q/k/v type t are uniform.
    const int h = n0 / 384;
    const int t = (n0 % 384) >> 7;
#pragma unroll
    for (int ni = 0; ni < 4; ++ni) {
      int dloc = wn * 64 + ni * 16 + fr;   // head-dim index d
      int n = n0 + dloc;
      float bv = bias[n];
#pragma unroll
      for (int mi = 0; mi < 4; ++mi) {
        int mbase = m0 + wm * 64 + mi * 16 + fq * 4;
#pragma unroll
        for (int j = 0; j < 4; ++j) {
          int m = mbase + j;
          int b = m >> 11, s = m & 2047;
          int bh = b * 16 + h;
          float v = acc[mi][ni][j] + bv;
          if (t == 0)      qb[((size_t)bh * 2048 + s) * 128 + dloc] = f2bf(v);
          else if (t == 1) kb[((size_t)bh * 2048 + s) * 128 + dloc] = f2bf(v);
          else             vtb[((size_t)bh * 128 + dloc) * 2048 + s] = f2bf(v);
        }
      }
    }
  }
}

// ---------------------------------------------------------------------------
// Causal flash attention (heavy-first, double-buffered, setprio).
// ---------------------------------------------------------------------------
__global__ __launch_bounds__(256)
void attn_kernel(const __hip_bfloat16* __restrict__ qb,
                 const __hip_bfloat16* __restrict__ kb,
                 const __hip_bfloat16* __restrict__ vtb,
                 __hip_bfloat16* __restrict__ ctx)
{
  __shared__ __hip_bfloat16 Ks[2][64 * 128];
  __shared__ __hip_bfloat16 Vts[2][128 * 64];
  __shared__ __hip_bfloat16 Ps[4][16 * 64];

  const int tid = threadIdx.x, lane = tid & 63, wave = tid >> 6;
  const int fr = lane & 15, fq = lane >> 4;
  const int blk = blockIdx.x;
  const int qi = 31 - (blk >> 5);
  const int bh = blk & 31;
  const int q0 = qi * 64;

  bf16x8 qf[4];
  const int qrow = q0 + wave * 16 + fr;
#pragma unroll
  for (int kf = 0; kf < 4; ++kf)
    qf[kf] = as_bf(*(const short8*)&qb[((size_t)bh * 2048 + qrow) * 128 + kf * 32 + fq * 8]);

  f32x4 acco[8] = {};
  float m_run[4] = {-1e30f, -1e30f, -1e30f, -1e30f};
  float l_run[4] = {0.f, 0.f, 0.f, 0.f};

  char* Pb = (char*)&Ps[wave][0];
  const int nt = qi + 1;

  auto STAGE = [&](int t, int buf) {
    const int k0t = t * 64;
#pragma unroll
    for (int i = 0; i < 4; ++i) {
      int c = wave * 4 + i;
      int kv = c * 4 + fq;
      int cb = (fr * 16) ^ ((kv & 7) << 4);
      gload16(&kb[((size_t)bh * 2048 + k0t + kv) * 128 + (cb >> 1)], &Ks[buf][c * 512]);
    }
#pragma unroll
    for (int i = 0; i < 4; ++i) {
      int c = wave * 4 + i;
      int d = c * 8 + (lane >> 3);
      int cb = ((lane & 7) * 16) ^ ((d & 7) << 4);
      gload16(&vtb[((size_t)bh * 128 + d) * 2048 + k0t + (cb >> 1)], &Vts[buf][c * 512]);
    }
  };

  STAGE(0, 0);
  __syncthreads();

  int cur = 0;
  for (int t = 0; t < nt; ++t) {
    if (t + 1 < nt) STAGE(t + 1, cur ^ 1);
    const char* Kb = (const char*)&Ks[cur][0];
    const char* Vb = (const char*)&Vts[cur][0];
    const int k0 = t * 64;

    f32x4 sacc[4] = {};
    __builtin_amdgcn_s_setprio(1);
#pragma unroll
    for (int kf = 0; kf < 4; ++kf) {
#pragma unroll
      for (int ni = 0; ni < 4; ++ni) {
        int kv = ni * 16 + fr;
        int cb = (kf * 64 + fq * 16) ^ ((kv & 7) << 4);
        bf16x8 kfr = as_bf(*(const short8*)(Kb + kv * 256 + cb));
        sacc[ni] = mfma16(qf[kf], kfr, sacc[ni]);
      }
    }
    __builtin_amdgcn_s_setprio(0);

    const float scale = 0.088388347648318447f;
    float sv[4][4];
    float rmax[4] = {-1e30f, -1e30f, -1e30f, -1e30f};
#pragma unroll
    for (int ni = 0; ni < 4; ++ni) {
      int kv_g = k0 + ni * 16 + fr;
#pragma unroll
      for (int j = 0; j < 4; ++j) {
        int q_g = q0 + wave * 16 + fq * 4 + j;
        float s = sacc[ni][j] * scale;
        if (kv_g > q_g) s = -10000.f;
        sv[ni][j] = s;
        rmax[j] = fmaxf(rmax[j], s);
      }
    }
#pragma unroll
    for (int off = 1; off < 16; off <<= 1)
#pragma unroll
      for (int j = 0; j < 4; ++j)
        rmax[j] = fmaxf(rmax[j], __shfl_xor(rmax[j], off));

    float alpha[4], rsum[4];
#pragma unroll
    for (int j = 0; j < 4; ++j) {
      float mn = fmaxf(m_run[j], rmax[j]);
      alpha[j] = __expf(m_run[j] - mn);
      m_run[j] = mn;
      rsum[j] = 0.f;
    }
#pragma unroll
    for (int ni = 0; ni < 4; ++ni) {
#pragma unroll
      for (int j = 0; j < 4; ++j) {
        float p = __expf(sv[ni][j] - m_run[j]);
        rsum[j] += p;
        int prow = fq * 4 + j;
        int cbw = ((ni * 16 + fr) * 2) ^ ((prow & 7) << 4);
        *(__hip_bfloat16*)(Pb + prow * 128 + cbw) = f2bf(p);
      }
    }
#pragma unroll
    for (int off = 1; off < 16; off <<= 1)
#pragma unroll
      for (int j = 0; j < 4; ++j)
        rsum[j] += __shfl_xor(rsum[j], off);
#pragma unroll
    for (int j = 0; j < 4; ++j)
      l_run[j] = l_run[j] * alpha[j] + rsum[j];

#pragma unroll
    for (int nd = 0; nd < 8; ++nd)
#pragma unroll
      for (int j = 0; j < 4; ++j)
        acco[nd][j] *= alpha[j];

    asm volatile("s_waitcnt lgkmcnt(0)" ::: "memory");
    __builtin_amdgcn_sched_barrier(0);

    __builtin_amdgcn_s_setprio(1);
#pragma unroll
    for (int kf2 = 0; kf2 < 2; ++kf2) {
      int cbp = (kf2 * 64 + fq * 16) ^ ((fr & 7) << 4);
      bf16x8 pa = as_bf(*(const short8*)(Pb + fr * 128 + cbp));
#pragma unroll
      for (int nd = 0; nd < 8; ++nd) {
        int d = nd * 16 + fr;
        int cbv = (kf2 * 64 + fq * 16) ^ ((d & 7) << 4);
        bf16x8 vfr = as_bf(*(const short8*)(Vb + d * 128 + cbv));
        acco[nd] = mfma16(pa, vfr, acco[nd]);
      }
    }
    __builtin_amdgcn_s_setprio(0);
    __syncthreads();
    cur ^= 1;
  }

  const int b = bh >> 4, h = bh & 15;
#pragma unroll
  for (int j = 0; j < 4; ++j) {
    float inv = 1.f / l_run[j];
    int s = q0 + wave * 16 + fq * 4 + j;
#pragma unroll
    for (int nd = 0; nd < 8; ++nd) {
      int d = nd * 16 + fr;
      ctx[(((size_t)b * 2048 + s) * 16 + h) * 128 + d] = f2bf(acco[nd][j] * inv);
    }
  }
}

// ---------------------------------------------------------------------------
extern "C" void kernel_launch(void* const* d_in, const int* in_sizes, int n_in,
                              void* d_out, int out_size, void* d_ws, size_t ws_size,
                              hipStream_t stream)
{
  (void)in_sizes; (void)n_in; (void)out_size; (void)ws_size;
  const float* x       = (const float*)d_in[0];
  const float* w_qkv   = (const float*)d_in[1];
  const float* b_qkv   = (const float*)d_in[2];
  const float* w_dense = (const float*)d_in[3];
  const float* b_dense = (const float*)d_in[4];
  float* out = (float*)d_out;

  char* ws = (char*)d_ws;
  __hip_bfloat16* x_bf     = (__hip_bfloat16*)(ws);                  // 16MB
  __hip_bfloat16* wqkv_t   = (__hip_bfloat16*)(ws + 16777216);       // 24MB
  __hip_bfloat16* wdense_t = (__hip_bfloat16*)(ws + 41943040);       // 8MB
  __hip_bfloat16* qb       = (__hip_bfloat16*)(ws + 50331648);       // 16MB
  __hip_bfloat16* kb       = (__hip_bfloat16*)(ws + 67108864);       // 16MB
  __hip_bfloat16* vtb      = (__hip_bfloat16*)(ws + 83886080);       // 16MB
  __hip_bfloat16* ctx      = (__hip_bfloat16*)(ws + 100663296);      // 16MB

  cvt_f32_bf16<<<4096, 256, 0, stream>>>(x, x_bf, 4096 * 2048);
  transpose_cvt<<<dim3(96, 32), 256, 0, stream>>>(w_qkv, wqkv_t, 2048, 6144);
  transpose_cvt<<<dim3(32, 32), 256, 0, stream>>>(w_dense, wdense_t, 2048, 2048);
  gemm_bt<<<dim3(48, 32), 256, 0, stream>>>(x_bf, wqkv_t, b_qkv, nullptr,
                                            qb, kb, vtb, 4096, 6144, 2048, 1);
  attn_kernel<<<1024, 256, 0, stream>>>(qb, kb, vtb, ctx);
  gemm_bt<<<dim3(16, 32), 256, 0, stream>>>(ctx, wdense_t, b_dense, out,
                                            nullptr, nullptr, nullptr, 4096, 2048, 2048, 0);
}

// Round 7
// 277.860 us; speedup vs baseline: 1.1330x; 1.0735x over previous
//
#include <hip/hip_runtime.h>
#include <hip/hip_bf16.h>
#include <stdint.h>

#define DEV __device__ __forceinline__

typedef __attribute__((ext_vector_type(8))) short short8;
typedef __attribute__((ext_vector_type(8))) __bf16 bf16x8;
typedef __attribute__((ext_vector_type(4))) float f32x4;

typedef const __attribute__((address_space(1))) uint32_t gu32;
typedef __attribute__((address_space(3))) uint32_t lu32;

DEV void gload16(const void* g, void* l) {
  __builtin_amdgcn_global_load_lds((gu32*)g, (lu32*)l, 16, 0, 0);
}

DEV f32x4 mfma16(bf16x8 a, bf16x8 b, f32x4 c) {
  return __builtin_amdgcn_mfma_f32_16x16x32_bf16(a, b, c, 0, 0, 0);
}

DEV __hip_bfloat16 f2bf(float x) { return __float2bfloat16(x); }
DEV bf16x8 as_bf(short8 v) { union { short8 s; bf16x8 b; } u; u.s = v; return u.b; }

// ---------------------------------------------------------------------------
// f32 -> bf16 elementwise convert (n multiple of 8).
// ---------------------------------------------------------------------------
__global__ __launch_bounds__(256)
void cvt_f32_bf16(const float* __restrict__ src, __hip_bfloat16* __restrict__ dst, int n)
{
  int i = (blockIdx.x * 256 + threadIdx.x) * 8;
  if (i >= n) return;
  f32x4 a = *(const f32x4*)&src[i];
  f32x4 b = *(const f32x4*)&src[i + 4];
  short8 o;
#pragma unroll
  for (int j = 0; j < 4; ++j) {
    o[j]     = __bfloat16_as_short(f2bf(a[j]));
    o[j + 4] = __bfloat16_as_short(f2bf(b[j]));
  }
  *(short8*)&dst[i] = o;
}

// ---------------------------------------------------------------------------
// Transpose f32 [K][N] -> bf16 [N][K], 64x64 tiles, 256 threads.
// ---------------------------------------------------------------------------
__global__ __launch_bounds__(256)
void transpose_cvt(const float* __restrict__ src,
                   __hip_bfloat16* __restrict__ dst,
                   int K, int N)
{
  __shared__ __hip_bfloat16 tile[64][72];
  const int tid = threadIdx.x;
  const int k0 = blockIdx.y * 64, n0 = blockIdx.x * 64;
  const int r = tid >> 3, c8 = tid & 7;
#pragma unroll
  for (int i = 0; i < 2; ++i) {
    int k = r + i * 32;
    f32x4 a = *(const f32x4*)&src[(size_t)(k0 + k) * N + n0 + c8 * 8];
    f32x4 b = *(const f32x4*)&src[(size_t)(k0 + k) * N + n0 + c8 * 8 + 4];
#pragma unroll
    for (int j = 0; j < 4; ++j) {
      tile[k][c8 * 8 + j]     = f2bf(a[j]);
      tile[k][c8 * 8 + 4 + j] = f2bf(b[j]);
    }
  }
  __syncthreads();
#pragma unroll
  for (int i = 0; i < 2; ++i) {
    int n = r + i * 32;
    short8 v;
#pragma unroll
    for (int j = 0; j < 8; ++j) v[j] = *(const short*)&tile[c8 * 8 + j][n];
    *(short8*)&dst[(size_t)(n0 + n) * K + k0 + c8 * 8] = v;
  }
}

// ---------------------------------------------------------------------------
// Deep-pipelined GEMM: C[M][N] = A[M][K] * Bt[N][K]^T + bias.
// BM=128, BN=256, BK=64; 512 threads = 8 waves (2M x 4N); per-wave 64x64.
// LDS 96KB: full double buffer (even K-tiles -> buf0, odd -> buf1).
// Iteration = 2 K-tiles, 4 phases x 16 MFMA. Staging in 128-row units
// (2 x gload16/thread); unit destinations are read-complete >=1 phase before
// issue (B is fully register-resident after each tile's first phase).
// Counted gates only: vmcnt(2)@ph2, vmcnt(4)@ph4 (vmcnt(0) only final iter).
// Raw s_barrier (no drain). T2 swizzle. T5 setprio. XCD column partition.
// mode 0: f32 C. mode 1: scatter q/k/v^T bf16.
// ---------------------------------------------------------------------------
__global__ __launch_bounds__(512, 2)
void gemm8p(const __hip_bfloat16* __restrict__ A,
            const __hip_bfloat16* __restrict__ Bt,
            const float* __restrict__ bias,
            float* __restrict__ C,
            __hip_bfloat16* __restrict__ qb,
            __hip_bfloat16* __restrict__ kb,
            __hip_bfloat16* __restrict__ vtb,
            int M, int N, int K, int mode)
{
  __shared__ __hip_bfloat16 As[2][128 * 64];
  __shared__ __hip_bfloat16 Bs[2][256 * 64];

  const int tid = threadIdx.x, lane = tid & 63, wave = tid >> 6;
  const int wm = wave >> 2, wn = wave & 3;

  // XCD column-partition swizzle (1-D grid; gridDim.x = (M/128)*(N/256))
  const int gx = N >> 8;                 // N-tiles
  const int cpx = gx >> 3;               // columns per XCD
  const int lin = blockIdx.x;
  const int xcd = lin & 7, t2 = lin >> 3;
  const int bx = xcd * cpx + (t2 % cpx);
  const int by = t2 / cpx;
  const int m0 = by * 128, n0 = bx * 256;

  const int fr = lane & 15, fq = lane >> 4;
  const int lrow = lane >> 3, lslot = lane & 7;

  // stage one 128-row unit: 2 x gload16/thread (wave-uniform LDS base + lane*16)
  auto stage = [&](const __hip_bfloat16* src, int srow0, int kc, char* dstTile) {
#pragma unroll
    for (int r = 0; r < 2; ++r) {
      int rbase = r * 64 + wave * 8;
      int rr = rbase + lrow;
      int col = (lslot ^ (rr & 7)) << 3;
      gload16(&src[(size_t)(srow0 + rr) * K + kc + col], dstTile + rbase * 128);
    }
  };

  char* A0 = (char*)&As[0][0];  char* A1 = (char*)&As[1][0];
  char* B0 = (char*)&Bs[0][0];  char* B1 = (char*)&Bs[1][0];

  auto rdA = [&](const char* base, int mi, int kk) {
    int row = wm * 64 + mi * 16 + fr;
    int cb = (kk * 64 + fq * 16) ^ ((row & 7) << 4);
    return as_bf(*(const short8*)(base + row * 128 + cb));
  };
  auto rdB = [&](const char* base, int ni, int kk) {
    int row = wn * 64 + ni * 16 + fr;
    int cb = (kk * 64 + fq * 16) ^ ((row & 7) << 4);
    return as_bf(*(const short8*)(base + row * 128 + cb));
  };

  f32x4 acc[4][4] = {};
  const int kt = K / 64;        // even
  const int nIt = kt / 2;

  // prologue: tiles 0 (buf0) and 1 (buf1): B0,B1,A each  (12 loads)
  stage(Bt, n0,       0, B0); stage(Bt, n0 + 128,  0, B0 + 128 * 128);
  stage(A,  m0,       0, A0);
  stage(Bt, n0,      64, B1); stage(Bt, n0 + 128, 64, B1 + 128 * 128);
  stage(A,  m0,      64, A1);
  asm volatile("s_waitcnt vmcnt(6)" ::: "memory");   // tile 0 landed
  __builtin_amdgcn_s_barrier();

  for (int j = 0; j < nIt; ++j) {
    const int T = 2 * j;
    const bool last = (j == nIt - 1);
    const int kc2 = (T + 2) * 64, kc3 = (T + 3) * 64;
    bf16x8 bfr[4][2], afr[2][2];

    // ---- ph1: read B(buf0) x8 + A(buf0,mi01) x4; MFMA mi{0,1} ----
#pragma unroll
    for (int ni = 0; ni < 4; ++ni) { bfr[ni][0] = rdB(B0, ni, 0); bfr[ni][1] = rdB(B0, ni, 1); }
#pragma unroll
    for (int mi = 0; mi < 2; ++mi) { afr[mi][0] = rdA(A0, mi, 0); afr[mi][1] = rdA(A0, mi, 1); }
    __builtin_amdgcn_s_barrier();
    __builtin_amdgcn_s_setprio(1);
#pragma unroll
    for (int kk = 0; kk < 2; ++kk)
#pragma unroll
      for (int mi = 0; mi < 2; ++mi)
#pragma unroll
        for (int ni = 0; ni < 4; ++ni)
          acc[mi][ni] = mfma16(afr[mi][kk], bfr[ni][kk], acc[mi][ni]);
    __builtin_amdgcn_s_setprio(0);
    __builtin_amdgcn_s_barrier();

    // ---- ph2: read A(buf0,mi23); stage b0.B0(T+2); gate vmcnt(2); MFMA ----
#pragma unroll
    for (int mi = 0; mi < 2; ++mi) { afr[mi][0] = rdA(A0, mi + 2, 0); afr[mi][1] = rdA(A0, mi + 2, 1); }
    if (!last) {
      stage(Bt, n0, kc2, B0);
      asm volatile("s_waitcnt vmcnt(2)" ::: "memory");   // tile T+1 landed
    } else {
      asm volatile("s_waitcnt vmcnt(0)" ::: "memory");
    }
    __builtin_amdgcn_s_barrier();
    __builtin_amdgcn_s_setprio(1);
#pragma unroll
    for (int kk = 0; kk < 2; ++kk)
#pragma unroll
      for (int mi = 0; mi < 2; ++mi)
#pragma unroll
        for (int ni = 0; ni < 4; ++ni)
          acc[mi + 2][ni] = mfma16(afr[mi][kk], bfr[ni][kk], acc[mi + 2][ni]);
    __builtin_amdgcn_s_setprio(0);
    __builtin_amdgcn_s_barrier();

    // ---- ph3: read B(buf1) x8 + A(buf1,mi01); stage b0.B1(T+2), b0.A(T+2) ----
#pragma unroll
    for (int ni = 0; ni < 4; ++ni) { bfr[ni][0] = rdB(B1, ni, 0); bfr[ni][1] = rdB(B1, ni, 1); }
#pragma unroll
    for (int mi = 0; mi < 2; ++mi) { afr[mi][0] = rdA(A1, mi, 0); afr[mi][1] = rdA(A1, mi, 1); }
    if (!last) {
      stage(Bt, n0 + 128, kc2, B0 + 128 * 128);
      stage(A,  m0,       kc2, A0);
    }
    __builtin_amdgcn_s_barrier();
    __builtin_amdgcn_s_setprio(1);
#pragma unroll
    for (int kk = 0; kk < 2; ++kk)
#pragma unroll
      for (int mi = 0; mi < 2; ++mi)
#pragma unroll
        for (int ni = 0; ni < 4; ++ni)
          acc[mi][ni] = mfma16(afr[mi][kk], bfr[ni][kk], acc[mi][ni]);
    __builtin_amdgcn_s_setprio(0);
    __builtin_amdgcn_s_barrier();

    // ---- ph4: read A(buf1,mi23); stage b1.B0/B1(T+3); gate vmcnt(4); MFMA;
    //          post-MFMA stage b1.A(T+3) ----
#pragma unroll
    for (int mi = 0; mi < 2; ++mi) { afr[mi][0] = rdA(A1, mi + 2, 0); afr[mi][1] = rdA(A1, mi + 2, 1); }
    if (!last) {
      stage(Bt, n0,       kc3, B1);
      stage(Bt, n0 + 128, kc3, B1 + 128 * 128);
      asm volatile("s_waitcnt vmcnt(4)" ::: "memory");   // tile T+2 landed
    } else {
      asm volatile("s_waitcnt vmcnt(0)" ::: "memory");
    }
    __builtin_amdgcn_s_barrier();
    __builtin_amdgcn_s_setprio(1);
#pragma unroll
    for (int kk = 0; kk < 2; ++kk)
#pragma unroll
      for (int mi = 0; mi < 2; ++mi)
#pragma unroll
        for (int ni = 0; ni < 4; ++ni)
          acc[mi + 2][ni] = mfma16(afr[mi][kk], bfr[ni][kk], acc[mi + 2][ni]);
    __builtin_amdgcn_s_setprio(0);
    if (!last) stage(A, m0, kc3, A1);                    // region free; covered by next G2
    __builtin_amdgcn_s_barrier();
  }

  // ---------------- epilogue ----------------
  if (mode == 0) {
#pragma unroll
    for (int ni = 0; ni < 4; ++ni) {
      int n = n0 + wn * 64 + ni * 16 + fr;
      float bv = bias[n];
#pragma unroll
      for (int mi = 0; mi < 4; ++mi) {
        int mbase = m0 + wm * 64 + mi * 16 + fq * 4;
#pragma unroll
        for (int jj = 0; jj < 4; ++jj)
          C[(size_t)(mbase + jj) * N + n] = acc[mi][ni][jj] + bv;
      }
    }
  } else {
#pragma unroll
    for (int ni = 0; ni < 4; ++ni) {
      const int nb = n0 + wn * 64 + ni * 16;     // 16-aligned
      const int h = nb / 384;
      const int rb = nb - h * 384;
      const int t3 = rb >> 7;
      const int dloc = (rb & 127) + fr;
      const float bv = bias[nb + fr];
#pragma unroll
      for (int mi = 0; mi < 4; ++mi) {
        const int mbase = m0 + wm * 64 + mi * 16 + fq * 4;
#pragma unroll
        for (int jj = 0; jj < 4; ++jj) {
          const int m = mbase + jj;
          const int b = m >> 11, s = m & 2047;
          const int bh = b * 16 + h;
          const float v = acc[mi][ni][jj] + bv;
          if (t3 == 0)      qb[((size_t)bh * 2048 + s) * 128 + dloc] = f2bf(v);
          else if (t3 == 1) kb[((size_t)bh * 2048 + s) * 128 + dloc] = f2bf(v);
          else              vtb[((size_t)bh * 128 + dloc) * 2048 + s] = f2bf(v);
        }
      }
    }
  }
}

// ---------------------------------------------------------------------------
// Causal flash attention (heavy-first, double-buffered, setprio).
// ---------------------------------------------------------------------------
__global__ __launch_bounds__(256)
void attn_kernel(const __hip_bfloat16* __restrict__ qb,
                 const __hip_bfloat16* __restrict__ kb,
                 const __hip_bfloat16* __restrict__ vtb,
                 __hip_bfloat16* __restrict__ ctx)
{
  __shared__ __hip_bfloat16 Ks[2][64 * 128];
  __shared__ __hip_bfloat16 Vts[2][128 * 64];
  __shared__ __hip_bfloat16 Ps[4][16 * 64];

  const int tid = threadIdx.x, lane = tid & 63, wave = tid >> 6;
  const int fr = lane & 15, fq = lane >> 4;
  const int blk = blockIdx.x;
  const int qi = 31 - (blk >> 5);
  const int bh = blk & 31;
  const int q0 = qi * 64;

  bf16x8 qf[4];
  const int qrow = q0 + wave * 16 + fr;
#pragma unroll
  for (int kf = 0; kf < 4; ++kf)
    qf[kf] = as_bf(*(const short8*)&qb[((size_t)bh * 2048 + qrow) * 128 + kf * 32 + fq * 8]);

  f32x4 acco[8] = {};
  float m_run[4] = {-1e30f, -1e30f, -1e30f, -1e30f};
  float l_run[4] = {0.f, 0.f, 0.f, 0.f};

  char* Pb = (char*)&Ps[wave][0];
  const int nt = qi + 1;

  auto STAGE = [&](int t, int buf) {
    const int k0t = t * 64;
#pragma unroll
    for (int i = 0; i < 4; ++i) {
      int c = wave * 4 + i;
      int kv = c * 4 + fq;
      int cb = (fr * 16) ^ ((kv & 7) << 4);
      gload16(&kb[((size_t)bh * 2048 + k0t + kv) * 128 + (cb >> 1)], &Ks[buf][c * 512]);
    }
#pragma unroll
    for (int i = 0; i < 4; ++i) {
      int c = wave * 4 + i;
      int d = c * 8 + (lane >> 3);
      int cb = ((lane & 7) * 16) ^ ((d & 7) << 4);
      gload16(&vtb[((size_t)bh * 128 + d) * 2048 + k0t + (cb >> 1)], &Vts[buf][c * 512]);
    }
  };

  STAGE(0, 0);
  __syncthreads();

  int cur = 0;
  for (int t = 0; t < nt; ++t) {
    if (t + 1 < nt) STAGE(t + 1, cur ^ 1);
    const char* Kb = (const char*)&Ks[cur][0];
    const char* Vb = (const char*)&Vts[cur][0];
    const int k0 = t * 64;

    f32x4 sacc[4] = {};
    __builtin_amdgcn_s_setprio(1);
#pragma unroll
    for (int kf = 0; kf < 4; ++kf) {
#pragma unroll
      for (int ni = 0; ni < 4; ++ni) {
        int kv = ni * 16 + fr;
        int cb = (kf * 64 + fq * 16) ^ ((kv & 7) << 4);
        bf16x8 kfr = as_bf(*(const short8*)(Kb + kv * 256 + cb));
        sacc[ni] = mfma16(qf[kf], kfr, sacc[ni]);
      }
    }
    __builtin_amdgcn_s_setprio(0);

    const float scale = 0.088388347648318447f;
    float sv[4][4];
    float rmax[4] = {-1e30f, -1e30f, -1e30f, -1e30f};
#pragma unroll
    for (int ni = 0; ni < 4; ++ni) {
      int kv_g = k0 + ni * 16 + fr;
#pragma unroll
      for (int j = 0; j < 4; ++j) {
        int q_g = q0 + wave * 16 + fq * 4 + j;
        float s = sacc[ni][j] * scale;
        if (kv_g > q_g) s = -10000.f;
        sv[ni][j] = s;
        rmax[j] = fmaxf(rmax[j], s);
      }
    }
#pragma unroll
    for (int off = 1; off < 16; off <<= 1)
#pragma unroll
      for (int j = 0; j < 4; ++j)
        rmax[j] = fmaxf(rmax[j], __shfl_xor(rmax[j], off));

    float alpha[4], rsum[4];
#pragma unroll
    for (int j = 0; j < 4; ++j) {
      float mn = fmaxf(m_run[j], rmax[j]);
      alpha[j] = __expf(m_run[j] - mn);
      m_run[j] = mn;
      rsum[j] = 0.f;
    }
#pragma unroll
    for (int ni = 0; ni < 4; ++ni) {
#pragma unroll
      for (int j = 0; j < 4; ++j) {
        float p = __expf(sv[ni][j] - m_run[j]);
        rsum[j] += p;
        int prow = fq * 4 + j;
        int cbw = ((ni * 16 + fr) * 2) ^ ((prow & 7) << 4);
        *(__hip_bfloat16*)(Pb + prow * 128 + cbw) = f2bf(p);
      }
    }
#pragma unroll
    for (int off = 1; off < 16; off <<= 1)
#pragma unroll
      for (int j = 0; j < 4; ++j)
        rsum[j] += __shfl_xor(rsum[j], off);
#pragma unroll
    for (int j = 0; j < 4; ++j)
      l_run[j] = l_run[j] * alpha[j] + rsum[j];

#pragma unroll
    for (int nd = 0; nd < 8; ++nd)
#pragma unroll
      for (int j = 0; j < 4; ++j)
        acco[nd][j] *= alpha[j];

    asm volatile("s_waitcnt lgkmcnt(0)" ::: "memory");
    __builtin_amdgcn_sched_barrier(0);

    __builtin_amdgcn_s_setprio(1);
#pragma unroll
    for (int kf2 = 0; kf2 < 2; ++kf2) {
      int cbp = (kf2 * 64 + fq * 16) ^ ((fr & 7) << 4);
      bf16x8 pa = as_bf(*(const short8*)(Pb + fr * 128 + cbp));
#pragma unroll
      for (int nd = 0; nd < 8; ++nd) {
        int d = nd * 16 + fr;
        int cbv = (kf2 * 64 + fq * 16) ^ ((d & 7) << 4);
        bf16x8 vfr = as_bf(*(const short8*)(Vb + d * 128 + cbv));
        acco[nd] = mfma16(pa, vfr, acco[nd]);
      }
    }
    __builtin_amdgcn_s_setprio(0);
    __syncthreads();
    cur ^= 1;
  }

  const int b = bh >> 4, h = bh & 15;
#pragma unroll
  for (int j = 0; j < 4; ++j) {
    float inv = 1.f / l_run[j];
    int s = q0 + wave * 16 + fq * 4 + j;
#pragma unroll
    for (int nd = 0; nd < 8; ++nd) {
      int d = nd * 16 + fr;
      ctx[(((size_t)b * 2048 + s) * 16 + h) * 128 + d] = f2bf(acco[nd][j] * inv);
    }
  }
}

// ---------------------------------------------------------------------------
extern "C" void kernel_launch(void* const* d_in, const int* in_sizes, int n_in,
                              void* d_out, int out_size, void* d_ws, size_t ws_size,
                              hipStream_t stream)
{
  (void)in_sizes; (void)n_in; (void)out_size; (void)ws_size;
  const float* x       = (const float*)d_in[0];
  const float* w_qkv   = (const float*)d_in[1];
  const float* b_qkv   = (const float*)d_in[2];
  const float* w_dense = (const float*)d_in[3];
  const float* b_dense = (const float*)d_in[4];
  float* out = (float*)d_out;

  char* ws = (char*)d_ws;
  __hip_bfloat16* x_bf     = (__hip_bfloat16*)(ws);                  // 16MB
  __hip_bfloat16* wqkv_t   = (__hip_bfloat16*)(ws + 16777216);       // 24MB
  __hip_bfloat16* wdense_t = (__hip_bfloat16*)(ws + 41943040);       // 8MB
  __hip_bfloat16* qb       = (__hip_bfloat16*)(ws + 50331648);       // 16MB
  __hip_bfloat16* kb       = (__hip_bfloat16*)(ws + 67108864);       // 16MB
  __hip_bfloat16* vtb      = (__hip_bfloat16*)(ws + 83886080);       // 16MB
  __hip_bfloat16* ctx      = (__hip_bfloat16*)(ws + 100663296);      // 16MB

  cvt_f32_bf16<<<4096, 256, 0, stream>>>(x, x_bf, 4096 * 2048);
  transpose_cvt<<<dim3(96, 32), 256, 0, stream>>>(w_qkv, wqkv_t, 2048, 6144);
  transpose_cvt<<<dim3(32, 32), 256, 0, stream>>>(w_dense, wdense_t, 2048, 2048);
  // QKV: grid (4096/128)*(6144/256) = 32*24 = 768 = 3 full generations
  gemm8p<<<768, 512, 0, stream>>>(x_bf, wqkv_t, b_qkv, nullptr,
                                  qb, kb, vtb, 4096, 6144, 2048, 1);
  attn_kernel<<<1024, 256, 0, stream>>>(qb, kb, vtb, ctx);
  // dense: grid (4096/128)*(2048/256) = 32*8 = 256 = 1 full generation
  gemm8p<<<256, 512, 0, stream>>>(ctx, wdense_t, b_dense, out,
                                  nullptr, nullptr, nullptr, 4096, 2048, 2048, 0);
}